// Round 1
// baseline (149.442 us; speedup 1.0000x reference)
//
#include <hip/hip_runtime.h>

#define DATA_BITS 108
#define SHIFT_BITS 7
#define F4_PER_ROW 27   // 108 floats = 27 float4 (row start always 16B-aligned: 432B rows)

// Kernel 1: collapse 7 shift bits -> single shift amount per row.
__global__ void shift_collapse_kernel(const int* __restrict__ shift,
                                      int* __restrict__ S, int rows) {
    int b = blockIdx.x * blockDim.x + threadIdx.x;
    const int stride = gridDim.x * blockDim.x;
    for (; b < rows; b += stride) {
        const int* p = shift + b * SHIFT_BITS;
        int s = 0;
        #pragma unroll
        for (int l = 0; l < SHIFT_BITS; ++l) {
            s = (s << 1) | (p[l] & 1);   // layer 0 is the MSB (2^6)
        }
        S[b] = s;
    }
}

// Kernel 2: one float4 output unit per thread iteration.
// out[b][i] = (i + S[b] < 108) ? X[b][i + S[b]] : 0
__global__ void barrel_shift_kernel(const float* __restrict__ X,
                                    const int* __restrict__ S,
                                    float* __restrict__ out, int total_units) {
    int u = blockIdx.x * blockDim.x + threadIdx.x;
    const int stride = gridDim.x * blockDim.x;
    for (; u < total_units; u += stride) {
        const int b = u / F4_PER_ROW;              // magic-mul, constant divisor
        const int q = u - b * F4_PER_ROW;
        const int s = S[b];
        const float* __restrict__ xrow = X + (long long)b * DATA_BITS;
        const int i0 = q * 4;
        float v[4];
        #pragma unroll
        for (int j = 0; j < 4; ++j) {
            const int src = i0 + j + s;
            v[j] = (src < DATA_BITS) ? xrow[src] : 0.0f;  // predicated; OOB lanes skip load
        }
        float4 r = make_float4(v[0], v[1], v[2], v[3]);
        *reinterpret_cast<float4*>(out + (long long)b * DATA_BITS + i0) = r;
    }
}

// Fallback (used only if ws is too small): recompute S inline per unit.
__global__ void barrel_shift_fused_kernel(const float* __restrict__ X,
                                          const int* __restrict__ shift,
                                          float* __restrict__ out, int total_units) {
    int u = blockIdx.x * blockDim.x + threadIdx.x;
    const int stride = gridDim.x * blockDim.x;
    for (; u < total_units; u += stride) {
        const int b = u / F4_PER_ROW;
        const int q = u - b * F4_PER_ROW;
        const int* p = shift + b * SHIFT_BITS;
        int s = 0;
        #pragma unroll
        for (int l = 0; l < SHIFT_BITS; ++l) s = (s << 1) | (p[l] & 1);
        const float* __restrict__ xrow = X + (long long)b * DATA_BITS;
        const int i0 = q * 4;
        float v[4];
        #pragma unroll
        for (int j = 0; j < 4; ++j) {
            const int src = i0 + j + s;
            v[j] = (src < DATA_BITS) ? xrow[src] : 0.0f;
        }
        float4 r = make_float4(v[0], v[1], v[2], v[3]);
        *reinterpret_cast<float4*>(out + (long long)b * DATA_BITS + i0) = r;
    }
}

extern "C" void kernel_launch(void* const* d_in, const int* in_sizes, int n_in,
                              void* d_out, int out_size, void* d_ws, size_t ws_size,
                              hipStream_t stream) {
    const float* X     = (const float*)d_in[0];
    const int*   shift = (const int*)d_in[1];
    float*       out   = (float*)d_out;

    const int rows = in_sizes[1] / SHIFT_BITS;          // 1,000,000
    const int total_units = rows * F4_PER_ROW;          // 27,000,000

    const int block = 256;
    const int grid2 = 2048;                              // grid-stride, ~51 iters/thread

    if (ws_size >= (size_t)rows * sizeof(int)) {
        int* S = (int*)d_ws;
        int grid1 = (rows + block - 1) / block;
        if (grid1 > 2048) grid1 = 2048;
        shift_collapse_kernel<<<grid1, block, 0, stream>>>(shift, S, rows);
        barrel_shift_kernel<<<grid2, block, 0, stream>>>(X, S, out, total_units);
    } else {
        barrel_shift_fused_kernel<<<grid2, block, 0, stream>>>(X, shift, out, total_units);
    }
}

// Round 2
// 146.977 us; speedup vs baseline: 1.0168x; 1.0168x over previous
//
#include <hip/hip_runtime.h>

#define DATA_BITS 108
#define SHIFT_BITS 7
#define F4_PER_ROW 27      // 108 floats = 27 float4; rows are 432B so row starts are 16B-aligned
#define ROWS_PER_TILE 256  // one row per thread for the S-collapse phase

typedef float f32x4 __attribute__((ext_vector_type(4)));

// Fused: per-block S-collapse into LDS, then 27 coalesced float4-store iterations.
// out[b][i] = (i + S[b] < 108) ? X[b][i + S[b]] : 0
__global__ __launch_bounds__(ROWS_PER_TILE) void barrel_fused_kernel(
    const float* __restrict__ X,
    const int* __restrict__ shift,
    float* __restrict__ out, int rows) {
    __shared__ int sS[ROWS_PER_TILE];

    const int row0 = blockIdx.x * ROWS_PER_TILE;
    const int t = threadIdx.x;

    // Phase 1: collapse 7 shift bits -> S for this block's rows (MSB-first).
    const int r = row0 + t;
    if (r < rows) {
        const int* p = shift + r * SHIFT_BITS;
        int s = 0;
        #pragma unroll
        for (int l = 0; l < SHIFT_BITS; ++l) s = (s << 1) | (p[l] & 1);
        sS[t] = s;
    }
    __syncthreads();

    // Phase 2: tile has nrows*27 float4 output units; 256 threads sweep them.
    const int nrows = min(ROWS_PER_TILE, rows - row0);
    const int units = nrows * F4_PER_ROW;
    for (int u = t; u < units; u += ROWS_PER_TILE) {
        const int rb = u / F4_PER_ROW;          // constant divisor -> magic mul
        const int q  = u - rb * F4_PER_ROW;
        const int s  = sS[rb];
        const float* __restrict__ xrow = X + (long long)(row0 + rb) * DATA_BITS;
        const int i0 = q * 4;
        f32x4 v;
        #pragma unroll
        for (int j = 0; j < 4; ++j) {
            const int src = i0 + j + s;
            v[j] = (src < DATA_BITS) ? xrow[src] : 0.0f;  // predicated; OOB lanes skip load
        }
        f32x4* dst = reinterpret_cast<f32x4*>(out + (long long)(row0 + rb) * DATA_BITS + i0);
        __builtin_nontemporal_store(v, dst);    // streaming write: don't pollute L2
    }
}

extern "C" void kernel_launch(void* const* d_in, const int* in_sizes, int n_in,
                              void* d_out, int out_size, void* d_ws, size_t ws_size,
                              hipStream_t stream) {
    const float* X     = (const float*)d_in[0];
    const int*   shift = (const int*)d_in[1];
    float*       out   = (float*)d_out;

    const int rows = in_sizes[1] / SHIFT_BITS;            // 1,000,000
    const int grid = (rows + ROWS_PER_TILE - 1) / ROWS_PER_TILE;  // 3907

    barrel_fused_kernel<<<grid, ROWS_PER_TILE, 0, stream>>>(X, shift, out, rows);
}

// Round 3
// 141.282 us; speedup vs baseline: 1.0578x; 1.0403x over previous
//
#include <hip/hip_runtime.h>

#define DATA_BITS 108
#define SHIFT_BITS 7
#define F4_PER_ROW 27      // 108 floats = 27 float4; rows are 432B so row starts are 16B-aligned
#define ROWS_PER_TILE 256  // one row per thread for the S-collapse phase

typedef float f32x4 __attribute__((ext_vector_type(4)));

// out[b][i] = (i + S[b] < 108) ? X[b][i + S[b]] : 0
// Loads are ALIGNED dwordx4: per-row misalignment m = S&3 is uniform, handled by
// a branchless register blend of two overlapping aligned windows.
__global__ __launch_bounds__(ROWS_PER_TILE) void barrel_fused_kernel(
    const float* __restrict__ X,
    const int* __restrict__ shift,
    float* __restrict__ out, int rows) {
    __shared__ int sS[ROWS_PER_TILE];

    const int row0 = blockIdx.x * ROWS_PER_TILE;
    const int t = threadIdx.x;
    const int N = rows * DATA_BITS;                 // 108,000,000 (fits int32)

    // Phase 1: collapse 7 shift bits -> S for this block's rows (MSB-first).
    const int r = row0 + t;
    if (r < rows) {
        const int* p = shift + r * SHIFT_BITS;
        int s = 0;
        #pragma unroll
        for (int l = 0; l < SHIFT_BITS; ++l) s = (s << 1) | (p[l] & 1);
        sS[t] = s;
    }
    __syncthreads();

    // Phase 2: nrows*27 float4 output units; 256 threads sweep them coalesced.
    const int nrows = min(ROWS_PER_TILE, rows - row0);
    const int units = nrows * F4_PER_ROW;
    for (int u = t; u < units; u += ROWS_PER_TILE) {
        const int rb = u / F4_PER_ROW;              // constant divisor -> magic mul
        const int q  = u - rb * F4_PER_ROW;
        const int s  = sS[rb];
        const int valid = DATA_BITS - s;            // #live output elems this row (may be <=0)
        const int i0 = q * 4;

        f32x4 rv = {0.f, 0.f, 0.f, 0.f};
        if (i0 < valid) {                           // fully-OOB units skip loads entirely
            const int s_al = s & ~3;
            const int m    = s & 3;
            const int idx_lo = (row0 + rb) * DATA_BITS + i0 + s_al;   // 16B-aligned
            int idx_hi = idx_lo + 4;
            idx_hi = min(idx_hi, N - 4);            // only engages on the final row; clamped
                                                    // elems are provably tail-masked below
            const f32x4 lo = *reinterpret_cast<const f32x4*>(X + idx_lo);
            const f32x4 hi = *reinterpret_cast<const f32x4*>(X + idx_hi);

            // branchless blend: r[j] = w[m + j], w = {lo, hi}
            const bool m2 = (m & 2) != 0;
            const bool m1 = (m & 1) != 0;
            const float t0 = m2 ? lo[2] : lo[0];
            const float t1 = m2 ? lo[3] : lo[1];
            const float t2 = m2 ? hi[0] : lo[2];
            const float t3 = m2 ? hi[1] : lo[3];
            const float t4 = m2 ? hi[2] : hi[0];
            rv[0] = m1 ? t1 : t0;
            rv[1] = m1 ? t2 : t1;
            rv[2] = m1 ? t3 : t2;
            rv[3] = m1 ? t4 : t3;

            // zero-mask the src >= 108 tail
            rv[0] = (i0 + 0 < valid) ? rv[0] : 0.f;
            rv[1] = (i0 + 1 < valid) ? rv[1] : 0.f;
            rv[2] = (i0 + 2 < valid) ? rv[2] : 0.f;
            rv[3] = (i0 + 3 < valid) ? rv[3] : 0.f;
        }
        f32x4* dst = reinterpret_cast<f32x4*>(out + (long long)(row0 + rb) * DATA_BITS + i0);
        __builtin_nontemporal_store(rv, dst);       // streaming write: don't pollute L2
    }
}

extern "C" void kernel_launch(void* const* d_in, const int* in_sizes, int n_in,
                              void* d_out, int out_size, void* d_ws, size_t ws_size,
                              hipStream_t stream) {
    const float* X     = (const float*)d_in[0];
    const int*   shift = (const int*)d_in[1];
    float*       out   = (float*)d_out;

    const int rows = in_sizes[1] / SHIFT_BITS;                      // 1,000,000
    const int grid = (rows + ROWS_PER_TILE - 1) / ROWS_PER_TILE;    // 3907

    barrel_fused_kernel<<<grid, ROWS_PER_TILE, 0, stream>>>(X, shift, out, rows);
}